// Round 4
// baseline (1855.219 us; speedup 1.0000x reference)
//
#include <hip/hip_runtime.h>
#include <math.h>

// ---------------------------------------------------------------------------
// GatedCrossAttention on MI355X (gfx950)
// B=32768, L=3, D=1024, H=16, DH=64
// Pipeline: wconv -> cvt(q,x->fp16) -> gemm(Q) -> gemm(KVR) -> attn
//           -> gemm(O) -> residual+LN
// GEMMs: fp16 MFMA 16x16x32, 128x128x64 tiles (m97 structure),
// global_load_lds width-16 staging, XOR-swizzled LDS (T2, both-sides rule),
// bijective XCD blockIdx swizzle (T1).
// Desk-verified r4: swizzle involution, C/D layout, grid nwg%8, re-poison
// safety. No changes vs r3 (no bench feedback yet).
// ---------------------------------------------------------------------------

using half8   = __attribute__((ext_vector_type(8))) _Float16;
using half4   = __attribute__((ext_vector_type(4))) _Float16;
using floatx4 = __attribute__((ext_vector_type(4))) float;

#define BTOT 32768
#define DM   1024
#define NH   16
#define LSEQ 3

__device__ __forceinline__ void gload_lds16(const void* g, void* l) {
  __builtin_amdgcn_global_load_lds(
      (const __attribute__((address_space(1))) void*)g,
      (__attribute__((address_space(3))) void*)l, 16, 0, 0);
}

// ---------------------------------------------------------------------------
// Activation conversion f32 -> fp16: q chunk (CB*1024) and x chunk
// (CB*3*1024) in one launch. Grid = CB*4 blocks; first CB*3 handle x.
// ---------------------------------------------------------------------------
__global__ __launch_bounds__(256) void acvt(
    const float* __restrict__ xc, _Float16* __restrict__ x16,
    const float* __restrict__ qc, _Float16* __restrict__ q16, int xblocks)
{
  const int blk = blockIdx.x;
  const float* src;
  _Float16* dst;
  size_t o;
  if (blk < xblocks) {
    o = ((size_t)blk * 256 + threadIdx.x) * 4;
    src = xc; dst = x16;
  } else {
    o = ((size_t)(blk - xblocks) * 256 + threadIdx.x) * 4;
    src = qc; dst = q16;
  }
  floatx4 a = *(const floatx4*)(src + o);
  half4 h;
  h[0] = (_Float16)a[0]; h[1] = (_Float16)a[1];
  h[2] = (_Float16)a[2]; h[3] = (_Float16)a[3];
  *(half4*)(dst + o) = h;
}

// ---------------------------------------------------------------------------
// Weight conversion: f32 -> fp16. Wk/Wv/Wr stacked into Wkvr16 [3072][1024].
// ---------------------------------------------------------------------------
__global__ __launch_bounds__(256) void wconv(
    const float* __restrict__ Wq, const float* __restrict__ Wk,
    const float* __restrict__ Wv, const float* __restrict__ Wr,
    const float* __restrict__ Wo,
    _Float16* __restrict__ Wq16, _Float16* __restrict__ Wkvr16,
    _Float16* __restrict__ Wo16)
{
  const int i = blockIdx.x * 256 + threadIdx.x;   // float4 units
  const size_t o = (size_t)i * 4;
  const size_t M1 = (size_t)1024 * 1024;
  floatx4 a;
  half4 h;
#define CVT(SRC, DST, OFF)                                        \
  a = *(const floatx4*)((SRC) + o);                               \
  h[0] = (_Float16)a[0]; h[1] = (_Float16)a[1];                   \
  h[2] = (_Float16)a[2]; h[3] = (_Float16)a[3];                   \
  *(half4*)((DST) + (OFF) + o) = h;
  CVT(Wq, Wq16, 0)
  CVT(Wo, Wo16, 0)
  CVT(Wk, Wkvr16, 0)
  CVT(Wv, Wkvr16, M1)
  CVT(Wr, Wkvr16, 2 * M1)
#undef CVT
}

// ---------------------------------------------------------------------------
// GEMM  C[M,N] = A[M,K] * Bw[N,K]^T  (torch Linear layout, K contiguous both)
// A, Bw fp16. OUT_HALF: write fp16, else f32.
// Block 256 thr = 4 waves (2x2 of 64x64 sub-tiles), tile 128x128, BK=64.
// LDS: linear dest for global_load_lds; XOR-chunk swizzle applied on the
// GLOBAL source and inverted on the ds_read side (both-sides rule, G21).
// ---------------------------------------------------------------------------
template <bool OUT_HALF>
__global__ __launch_bounds__(256) void gemm_bt(
    const _Float16* __restrict__ A, const _Float16* __restrict__ Bw,
    void* __restrict__ Cout, int M, int N, int K)
{
  __shared__ __attribute__((aligned(16))) char As[128 * 128];
  __shared__ __attribute__((aligned(16))) char Bs[128 * 128];

  const int tid  = threadIdx.x;
  const int lane = tid & 63;
  const int wave = tid >> 6;
  const int wr = wave >> 1, wc = wave & 1;
  const int l15 = lane & 15, lk = lane >> 4;

  // bijective XCD swizzle (nwg % 8 == 0 for all our grids)
  const int nwg = gridDim.x * gridDim.y;
  int wgid = blockIdx.y * gridDim.x + blockIdx.x;
  wgid = (wgid & 7) * (nwg >> 3) + (wgid >> 3);
  const int bx = wgid % gridDim.x;
  const int by = wgid / gridDim.x;

  const int col0 = bx * 128;
  const int row0 = by * 128;

  floatx4 acc[4][4] = {};

  const int nK = K >> 6;
  for (int kt = 0; kt < nK; ++kt) {
    const int k0 = kt << 6;
    // ---- stage A and B tiles: 128 rows x 64 fp16 (128 B/row) each ----
    {
      const char* gA = (const char*)A + ((size_t)row0 * K + k0) * 2;
      const char* gB = (const char*)Bw + ((size_t)col0 * K + k0) * 2;
      #pragma unroll
      for (int it = 0; it < 4; ++it) {
        const int off = it * 4096 + tid * 16;
        const int row = off >> 7;          // 128 B per LDS row
        const int ch  = (off >> 4) & 7;    // 16 B chunk within row
        const int sch = ch ^ (row & 7);    // inverse-swizzled global chunk
        gload_lds16(gA + (size_t)row * ((size_t)K * 2) + (sch << 4), As + off);
        gload_lds16(gB + (size_t)row * ((size_t)K * 2) + (sch << 4), Bs + off);
      }
    }
    __syncthreads();
    // ---- compute ----
    #pragma unroll
    for (int kk = 0; kk < 64; kk += 32) {
      half8 af[4], bf[4];
      const int c = (kk >> 3) + lk;        // 16B chunk index within row
      #pragma unroll
      for (int m = 0; m < 4; ++m) {
        const int rw = wr * 64 + m * 16 + l15;
        af[m] = *(const half8*)(As + rw * 128 + ((c ^ (rw & 7)) << 4));
      }
      #pragma unroll
      for (int n = 0; n < 4; ++n) {
        const int rw = wc * 64 + n * 16 + l15;
        bf[n] = *(const half8*)(Bs + rw * 128 + ((c ^ (rw & 7)) << 4));
      }
      #pragma unroll
      for (int m = 0; m < 4; ++m)
        #pragma unroll
        for (int n = 0; n < 4; ++n)
          acc[m][n] = __builtin_amdgcn_mfma_f32_16x16x32_f16(
              af[m], bf[n], acc[m][n], 0, 0, 0);
    }
    __syncthreads();
  }
  // ---- epilogue: C/D layout col=lane&15, row=(lane>>4)*4+reg ----
  #pragma unroll
  for (int m = 0; m < 4; ++m) {
    const int rbase = row0 + wr * 64 + m * 16 + (lk << 2);
    #pragma unroll
    for (int r = 0; r < 4; ++r) {
      const size_t rowoff = (size_t)(rbase + r) * N;
      #pragma unroll
      for (int n = 0; n < 4; ++n) {
        const int col = col0 + wc * 64 + n * 16 + l15;
        const float v = acc[m][n][r];
        if constexpr (OUT_HALF)
          ((_Float16*)Cout)[rowoff + col] = (_Float16)v;
        else
          ((float*)Cout)[rowoff + col] = v;
      }
    }
  }
}

// ---------------------------------------------------------------------------
// Attention: 1 wave per batch row. lane -> head h = lane>>2, part p = lane&3
// (16 dims each). scores over L=3, softmax, sigmoid(R)*V weighted sum.
// ---------------------------------------------------------------------------
__global__ __launch_bounds__(256) void attn_kernel(
    const _Float16* __restrict__ Q16, const _Float16* __restrict__ KVR,
    _Float16* __restrict__ AV16, float* __restrict__ attn_out,
    size_t batch0)
{
  const int lane = threadIdx.x & 63;
  const int wave = threadIdx.x >> 6;
  const size_t b = (size_t)blockIdx.x * 4 + wave;   // local batch index
  const int h = lane >> 2, p = lane & 3;
  const int doff = h * 64 + p * 16;

  float qv[16];
  {
    const half8* qp = (const half8*)(Q16 + b * 1024 + doff);
    half8 q0 = qp[0], q1 = qp[1];
    #pragma unroll
    for (int i = 0; i < 8; ++i) { qv[i] = (float)q0[i]; qv[8 + i] = (float)q1[i]; }
  }
  float sc[LSEQ];
  #pragma unroll
  for (int l = 0; l < LSEQ; ++l) {
    const half8* kp = (const half8*)(KVR + (b * 3 + l) * 3072 + doff);
    half8 k0 = kp[0], k1 = kp[1];
    float d = 0.f;
    #pragma unroll
    for (int i = 0; i < 8; ++i)
      d += qv[i] * (float)k0[i] + qv[8 + i] * (float)k1[i];
    d += __shfl_xor(d, 1);
    d += __shfl_xor(d, 2);
    sc[l] = d * 0.125f;   // 1/sqrt(64)
  }
  const float mx = fmaxf(sc[0], fmaxf(sc[1], sc[2]));
  const float e0 = __expf(sc[0] - mx), e1 = __expf(sc[1] - mx),
              e2 = __expf(sc[2] - mx);
  const float inv = 1.f / (e0 + e1 + e2);
  const float at0 = e0 * inv, at1 = e1 * inv, at2 = e2 * inv;
  if (p == 0) {
    float* ao = attn_out + ((batch0 + b) * NH + h) * LSEQ;
    ao[0] = at0; ao[1] = at1; ao[2] = at2;
  }
  const float atw[LSEQ] = {at0, at1, at2};
  float av[16] = {};
  #pragma unroll
  for (int l = 0; l < LSEQ; ++l) {
    const half8* vp = (const half8*)(KVR + (b * 3 + l) * 3072 + 1024 + doff);
    const half8* rp = (const half8*)(KVR + (b * 3 + l) * 3072 + 2048 + doff);
    half8 v0 = vp[0], v1 = vp[1], r0 = rp[0], r1 = rp[1];
    #pragma unroll
    for (int i = 0; i < 8; ++i) {
      const float g0 = 1.f / (1.f + __expf(-(float)r0[i]));
      const float g1 = 1.f / (1.f + __expf(-(float)r1[i]));
      av[i]     += atw[l] * g0 * (float)v0[i];
      av[8 + i] += atw[l] * g1 * (float)v1[i];
    }
  }
  half8 o0, o1;
  #pragma unroll
  for (int i = 0; i < 8; ++i) { o0[i] = (_Float16)av[i]; o1[i] = (_Float16)av[8 + i]; }
  half8* op = (half8*)(AV16 + b * 1024 + doff);
  op[0] = o0; op[1] = o1;
}

// ---------------------------------------------------------------------------
// Residual + LayerNorm: 1 wave per row (1024 elems, 16 per lane).
// ---------------------------------------------------------------------------
__global__ __launch_bounds__(256) void ln_kernel(
    const float* __restrict__ qres, const float* __restrict__ outlin,
    const float* __restrict__ gamma, const float* __restrict__ beta,
    float* __restrict__ out)
{
  const int lane = threadIdx.x & 63;
  const size_t r = (size_t)blockIdx.x * 4 + (threadIdx.x >> 6);
  const size_t base = r * 1024 + lane * 16;
  floatx4 y[4];
  float s = 0.f, ss = 0.f;
  #pragma unroll
  for (int i = 0; i < 4; ++i) {
    floatx4 a  = *(const floatx4*)(qres + base + i * 4);
    floatx4 bb = *(const floatx4*)(outlin + base + i * 4);
    y[i] = a + bb;
    #pragma unroll
    for (int j = 0; j < 4; ++j) { s += y[i][j]; ss += y[i][j] * y[i][j]; }
  }
  #pragma unroll
  for (int o = 1; o < 64; o <<= 1) {
    s  += __shfl_xor(s, o);
    ss += __shfl_xor(ss, o);
  }
  const float mu  = s * (1.f / 1024.f);
  const float var = ss * (1.f / 1024.f) - mu * mu;
  const float rs  = rsqrtf(var + 1e-5f);
  #pragma unroll
  for (int i = 0; i < 4; ++i) {
    floatx4 g  = *(const floatx4*)(gamma + lane * 16 + i * 4);
    floatx4 be = *(const floatx4*)(beta + lane * 16 + i * 4);
    floatx4 o;
    #pragma unroll
    for (int j = 0; j < 4; ++j)
      o[j] = (y[i][j] - mu) * rs * g[j] + be[j];
    *(floatx4*)(out + base + i * 4) = o;
  }
}

// ---------------------------------------------------------------------------
extern "C" void kernel_launch(void* const* d_in, const int* in_sizes, int n_in,
                              void* d_out, int out_size, void* d_ws, size_t ws_size,
                              hipStream_t stream)
{
  const float* q     = (const float*)d_in[0];
  const float* x     = (const float*)d_in[1];
  const float* Wq    = (const float*)d_in[2];
  const float* Wk    = (const float*)d_in[3];
  const float* Wv    = (const float*)d_in[4];
  const float* Wr    = (const float*)d_in[5];
  const float* Wo    = (const float*)d_in[6];
  const float* gamma = (const float*)d_in[7];
  const float* beta  = (const float*)d_in[8];

  float* out      = (float*)d_out;
  float* attn_out = out + (size_t)BTOT * DM;   // outputs concatenated flat

  char* ws = (char*)d_ws;
  _Float16* Wq16   = (_Float16*)ws; ws += (size_t)1024 * 1024 * 2;
  _Float16* Wkvr16 = (_Float16*)ws; ws += (size_t)3072 * 1024 * 2;
  _Float16* Wo16   = (_Float16*)ws; ws += (size_t)1024 * 1024 * 2;

  const size_t wbytes = (size_t)10 * 1024 * 1024;
  const size_t rem = ws_size > wbytes ? ws_size - wbytes : 0;
  // per-batch scratch (bytes):
  //   x16 6144 + q16 2048 + Q16 2048 + KVR 18432 + AV16 2048 + OUTL 4096
  int CB = 128;
  for (int c = BTOT; c >= 128; c >>= 1)
    if ((size_t)c * 34816 <= rem) { CB = c; break; }

  _Float16* x16  = (_Float16*)ws; ws += (size_t)CB * 3 * 1024 * 2;
  _Float16* q16  = (_Float16*)ws; ws += (size_t)CB * 1024 * 2;
  _Float16* Q16  = (_Float16*)ws; ws += (size_t)CB * 1024 * 2;
  _Float16* KVR  = (_Float16*)ws; ws += (size_t)CB * 3 * 3072 * 2;
  _Float16* AV16 = (_Float16*)ws; ws += (size_t)CB * 1024 * 2;
  float*    OUTL = (float*)ws;

  wconv<<<dim3(1024), dim3(256), 0, stream>>>(Wq, Wk, Wv, Wr, Wo,
                                              Wq16, Wkvr16, Wo16);

  const int xblk = (CB * LSEQ * DM) / 1024;   // x conversion blocks
  const int qblk = (CB * DM) / 1024;          // q conversion blocks
  for (int c = 0; c < BTOT; c += CB) {
    const float* qc = q + (size_t)c * DM;
    const float* xc = x + (size_t)c * LSEQ * DM;
    // activations -> fp16 (one launch: x chunk then q chunk)
    acvt<<<dim3(xblk + qblk), dim3(256), 0, stream>>>(xc, x16, qc, q16, xblk);
    // projections
    gemm_bt<true><<<dim3(1024 / 128, CB / 128), dim3(256), 0, stream>>>(
        q16, Wq16, Q16, CB, 1024, 1024);
    gemm_bt<true><<<dim3(3072 / 128, (3 * CB) / 128), dim3(256), 0, stream>>>(
        x16, Wkvr16, KVR, 3 * CB, 3072, 1024);
    // attention + gated V
    attn_kernel<<<dim3(CB / 4), dim3(256), 0, stream>>>(Q16, KVR, AV16,
                                                        attn_out, (size_t)c);
    // output projection
    gemm_bt<false><<<dim3(1024 / 128, CB / 128), dim3(256), 0, stream>>>(
        AV16, Wo16, OUTL, CB, 1024, 1024);
    // residual + LN
    ln_kernel<<<dim3(CB / 4), dim3(256), 0, stream>>>(qc, OUTL, gamma, beta,
                                                      out + (size_t)c * DM);
  }
}

// Round 5
// 1618.990 us; speedup vs baseline: 1.1459x; 1.1459x over previous
//
#include <hip/hip_runtime.h>
#include <math.h>

// ---------------------------------------------------------------------------
// GatedCrossAttention on MI355X (gfx950)
// B=32768, L=3, D=1024, H=16, DH=64
// Pipeline: wconv -> cvt(q,x->fp16) -> gemm(Q) -> gemm(KVR) -> attn
//           -> gemm(O) -> residual+LN
// r5: 256x256 8-phase GEMM (T2 swizzle + T3/T4 counted vmcnt + T5 setprio)
// replaces the m97-style 128x128 loop for all three projections (CB==32768
// path). KVR measured r4: 765us @ MfmaUtil 38.6% -> predicted ~480us @ ~57%.
// ---------------------------------------------------------------------------

using half8   = __attribute__((ext_vector_type(8))) _Float16;
using half4   = __attribute__((ext_vector_type(4))) _Float16;
using floatx4 = __attribute__((ext_vector_type(4))) float;

#define BTOT 32768
#define DM   1024
#define NH   16
#define LSEQ 3

__device__ __forceinline__ void gload_lds16(const void* g, void* l) {
  __builtin_amdgcn_global_load_lds(
      (const __attribute__((address_space(1))) void*)g,
      (__attribute__((address_space(3))) void*)l, 16, 0, 0);
}

// counted vmcnt gate, order-pinned (rule #18: sched_barrier around asm wait)
#define WAITVM(N) do { __builtin_amdgcn_sched_barrier(0);            \
  asm volatile("s_waitcnt vmcnt(" #N ")" ::: "memory");              \
  __builtin_amdgcn_sched_barrier(0); } while (0)

// ---------------------------------------------------------------------------
// Activation conversion f32 -> fp16 (x chunk then q chunk in one launch).
// ---------------------------------------------------------------------------
__global__ __launch_bounds__(256) void acvt(
    const float* __restrict__ xc, _Float16* __restrict__ x16,
    const float* __restrict__ qc, _Float16* __restrict__ q16, int xblocks)
{
  const int blk = blockIdx.x;
  const float* src;
  _Float16* dst;
  size_t o;
  if (blk < xblocks) {
    o = ((size_t)blk * 256 + threadIdx.x) * 4;
    src = xc; dst = x16;
  } else {
    o = ((size_t)(blk - xblocks) * 256 + threadIdx.x) * 4;
    src = qc; dst = q16;
  }
  floatx4 a = *(const floatx4*)(src + o);
  half4 h;
  h[0] = (_Float16)a[0]; h[1] = (_Float16)a[1];
  h[2] = (_Float16)a[2]; h[3] = (_Float16)a[3];
  *(half4*)(dst + o) = h;
}

// ---------------------------------------------------------------------------
// Weight conversion: f32 -> fp16. Wk/Wv/Wr stacked into Wkvr16 [3072][1024].
// ---------------------------------------------------------------------------
__global__ __launch_bounds__(256) void wconv(
    const float* __restrict__ Wq, const float* __restrict__ Wk,
    const float* __restrict__ Wv, const float* __restrict__ Wr,
    const float* __restrict__ Wo,
    _Float16* __restrict__ Wq16, _Float16* __restrict__ Wkvr16,
    _Float16* __restrict__ Wo16)
{
  const int i = blockIdx.x * 256 + threadIdx.x;
  const size_t o = (size_t)i * 4;
  const size_t M1 = (size_t)1024 * 1024;
  floatx4 a;
  half4 h;
#define CVT(SRC, DST, OFF)                                        \
  a = *(const floatx4*)((SRC) + o);                               \
  h[0] = (_Float16)a[0]; h[1] = (_Float16)a[1];                   \
  h[2] = (_Float16)a[2]; h[3] = (_Float16)a[3];                   \
  *(half4*)((DST) + (OFF) + o) = h;
  CVT(Wq, Wq16, 0)
  CVT(Wo, Wo16, 0)
  CVT(Wk, Wkvr16, 0)
  CVT(Wv, Wkvr16, M1)
  CVT(Wr, Wkvr16, 2 * M1)
#undef CVT
}

// ---------------------------------------------------------------------------
// Legacy 128x128 GEMM (m97 structure) — fallback path, validated r4.
// ---------------------------------------------------------------------------
template <bool OUT_HALF>
__global__ __launch_bounds__(256) void gemm_bt(
    const _Float16* __restrict__ A, const _Float16* __restrict__ Bw,
    void* __restrict__ Cout, int M, int N, int K)
{
  __shared__ __attribute__((aligned(16))) char As[128 * 128];
  __shared__ __attribute__((aligned(16))) char Bs[128 * 128];

  const int tid  = threadIdx.x;
  const int lane = tid & 63;
  const int wave = tid >> 6;
  const int wr = wave >> 1, wc = wave & 1;
  const int l15 = lane & 15, lk = lane >> 4;

  const int nwg = gridDim.x * gridDim.y;
  int wgid = blockIdx.y * gridDim.x + blockIdx.x;
  wgid = (wgid & 7) * (nwg >> 3) + (wgid >> 3);
  const int bx = wgid % gridDim.x;
  const int by = wgid / gridDim.x;

  const int col0 = bx * 128;
  const int row0 = by * 128;

  floatx4 acc[4][4] = {};

  const int nK = K >> 6;
  for (int kt = 0; kt < nK; ++kt) {
    const int k0 = kt << 6;
    {
      const char* gA = (const char*)A + ((size_t)row0 * K + k0) * 2;
      const char* gB = (const char*)Bw + ((size_t)col0 * K + k0) * 2;
      #pragma unroll
      for (int it = 0; it < 4; ++it) {
        const int off = it * 4096 + tid * 16;
        const int row = off >> 7;
        const int ch  = (off >> 4) & 7;
        const int sch = ch ^ (row & 7);
        gload_lds16(gA + (size_t)row * ((size_t)K * 2) + (sch << 4), As + off);
        gload_lds16(gB + (size_t)row * ((size_t)K * 2) + (sch << 4), Bs + off);
      }
    }
    __syncthreads();
    #pragma unroll
    for (int kk = 0; kk < 64; kk += 32) {
      half8 af[4], bf[4];
      const int c = (kk >> 3) + lk;
      #pragma unroll
      for (int m = 0; m < 4; ++m) {
        const int rw = wr * 64 + m * 16 + l15;
        af[m] = *(const half8*)(As + rw * 128 + ((c ^ (rw & 7)) << 4));
      }
      #pragma unroll
      for (int n = 0; n < 4; ++n) {
        const int rw = wc * 64 + n * 16 + l15;
        bf[n] = *(const half8*)(Bs + rw * 128 + ((c ^ (rw & 7)) << 4));
      }
      #pragma unroll
      for (int m = 0; m < 4; ++m)
        #pragma unroll
        for (int n = 0; n < 4; ++n)
          acc[m][n] = __builtin_amdgcn_mfma_f32_16x16x32_f16(
              af[m], bf[n], acc[m][n], 0, 0, 0);
    }
    __syncthreads();
  }
  #pragma unroll
  for (int m = 0; m < 4; ++m) {
    const int rbase = row0 + wr * 64 + m * 16 + (lk << 2);
    #pragma unroll
    for (int r = 0; r < 4; ++r) {
      const size_t rowoff = (size_t)(rbase + r) * N;
      #pragma unroll
      for (int n = 0; n < 4; ++n) {
        const int col = col0 + wc * 64 + n * 16 + l15;
        const float v = acc[m][n][r];
        if constexpr (OUT_HALF)
          ((_Float16*)Cout)[rowoff + col] = (_Float16)v;
        else
          ((float*)Cout)[rowoff + col] = v;
      }
    }
  }
}

// ---------------------------------------------------------------------------
// 256x256 8-phase GEMM (T2+T3+T4+T5). 512 thr = 8 waves (2M x 4N).
// Per-wave output 128x64. BK=64, 2 K-tiles per loop iteration, double-buffered
// LDS (128 KiB). One half-tile (128 rows x 64 fp16 = 16 KB) staged per phase;
// counted vmcnt(2) gates only at phases 4/8. Swizzle: chunk ^= row&7 (16B
// chunks), applied on the global source, inverted on ds_read (G21).
// Phase schedule (iteration computes tiles T=2it [buf0], T+1 [buf1]):
//   ph1 (b0,k0,mh0)+B  stage T+1.Ah0->b1   | ph5 (b1,k0,mh0)+B  stage T+2.Ah0->b0
//   ph2 (b0,k0,mh1)    stage T+1.Ah1->b1   | ph6 (b1,k0,mh1)    stage T+2.Ah1->b0
//   ph3 (b0,k1,mh0)+B  stage T+1.Bh1->b1   | ph7 (b1,k1,mh0)+B  stage T+2.Bh1->b0
//   ph4 (b0,k1,mh1)    stage T+2.Bh0->b0,  | ph8 (b1,k1,mh1)    stage T+3.Bh0->b1,
//        vmcnt(2) [T+1 landed]             |      vmcnt(2) [T+2 landed]
// Every overwrite targets a region whose last ds_read completed >=1 barrier
// earlier (A halves last read ph4/ph8; B halves last read ph3/ph7).
// ---------------------------------------------------------------------------
template <int BUF, int CK, int MH, bool LOADB, typename SF, typename GF>
__device__ __forceinline__ void phase(const char* ldsp, int aoff, int boff,
                                      int ca0, int ca1,
                                      half8 (&bf)[4], floatx4 (&acc)[8][4],
                                      SF&& stage, GF&& gate)
{
  const int ca = CK ? ca1 : ca0;
  half8 af[4];
  #pragma unroll
  for (int m = 0; m < 4; ++m)
    af[m] = *(const half8*)(ldsp + BUF * 32768 + aoff + (MH * 4 + m) * 2048 + ca);
  if constexpr (LOADB) {
    #pragma unroll
    for (int n = 0; n < 4; ++n)
      bf[n] = *(const half8*)(ldsp + 65536 + BUF * 32768 + boff + n * 2048 + ca);
  }
  stage();
  gate();
  __builtin_amdgcn_s_barrier();
  __builtin_amdgcn_s_setprio(1);
  #pragma unroll
  for (int m = 0; m < 4; ++m)
    #pragma unroll
    for (int n = 0; n < 4; ++n)
      acc[MH * 4 + m][n] = __builtin_amdgcn_mfma_f32_16x16x32_f16(
          af[m], bf[n], acc[MH * 4 + m][n], 0, 0, 0);
  __builtin_amdgcn_s_setprio(0);
  __builtin_amdgcn_s_barrier();
}

template <bool OUT_HALF>
__global__ __launch_bounds__(512, 2) void gemm256(
    const _Float16* __restrict__ A, const _Float16* __restrict__ Bw,
    void* __restrict__ Cout, int M, int N, int K)
{
  __shared__ __attribute__((aligned(16))) char lds[131072];
  const int tid  = threadIdx.x;
  const int lane = tid & 63;
  const int wave = tid >> 6;
  const int wm = wave >> 2, wn = wave & 3;
  const int l15 = lane & 15, lk = lane >> 4;
  const int sx = l15 & 7;

  // bijective XCD swizzle (caller guarantees nwg % 8 == 0)
  const int nwg = gridDim.x * gridDim.y;
  int wgid = blockIdx.y * gridDim.x + blockIdx.x;
  wgid = (wgid & 7) * (nwg >> 3) + (wgid >> 3);
  const int bx = wgid % gridDim.x;
  const int by = wgid / gridDim.x;
  const int col0 = bx * 256, row0 = by * 256;

  const size_t Kb = (size_t)K * 2;            // bytes per row
  const char* gA = (const char*)A + (size_t)row0 * Kb;
  const char* gB = (const char*)Bw + (size_t)col0 * Kb;
  char* ldsc = (char*)lds;

  auto stA = [&](int buf, int half, int kt) {
    #pragma unroll
    for (int ld = 0; ld < 2; ++ld) {
      const int off = ld * 8192 + tid * 16;
      const int r = off >> 7;                        // row within half
      const int sch = ((off >> 4) & 7) ^ (r & 7);    // inverse-swz source chunk
      gload_lds16(gA + (size_t)(half * 128 + r) * Kb + kt * 128 + (sch << 4),
                  ldsc + buf * 32768 + half * 16384 + off);
    }
  };
  auto stB = [&](int buf, int half, int kt) {
    #pragma unroll
    for (int ld = 0; ld < 2; ++ld) {
      const int off = ld * 8192 + tid * 16;
      const int r = off >> 7;
      const int sch = ((off >> 4) & 7) ^ (r & 7);
      gload_lds16(gB + (size_t)(half * 128 + r) * Kb + kt * 128 + (sch << 4),
                  ldsc + 65536 + buf * 32768 + half * 16384 + off);
    }
  };

  const int aoff = (wm * 128 + l15) * 128;    // LDS byte base of A frag rows
  const int boff = (wn * 64 + l15) * 128;     // LDS byte base of B frag rows
  const int ca0 = (lk ^ sx) << 4;             // chunk addr, kk=0 (chunks 0-3)
  const int ca1 = ((4 + lk) ^ sx) << 4;       // chunk addr, kk=32 (chunks 4-7)

  floatx4 acc[8][4] = {};
  half8 bf[4];

  // prologue: tile0 -> buf0 (4 halves), tile1.Bh0 -> buf1; tile0 landed.
  stA(0, 0, 0); stA(0, 1, 0); stB(0, 0, 0); stB(0, 1, 0);
  stB(1, 0, 1);
  WAITVM(2);
  __builtin_amdgcn_s_barrier();

  const int nIt = K >> 7;                     // 2 K-tiles (BK=64) per iter
  for (int it = 0; it < nIt; ++it) {
    const int t1 = 2 * it + 1, t2 = 2 * it + 2, t3 = 2 * it + 3;
    const bool lastit = (it == nIt - 1);
    auto g0 = [&] {};
    auto g2 = [&] { if (!lastit) { WAITVM(2); } else { WAITVM(0); } };
    phase<0, 0, 0, true >(ldsc, aoff, boff, ca0, ca1, bf, acc,
                          [&] { stA(1, 0, t1); }, g0);
    phase<0, 0, 1, false>(ldsc, aoff, boff, ca0, ca1, bf, acc,
                          [&] { stA(1, 1, t1); }, g0);
    phase<0, 1, 0, true >(ldsc, aoff, boff, ca0, ca1, bf, acc,
                          [&] { stB(1, 1, t1); }, g0);
    phase<0, 1, 1, false>(ldsc, aoff, boff, ca0, ca1, bf, acc,
                          [&] { if (!lastit) stB(0, 0, t2); }, g2);
    phase<1, 0, 0, true >(ldsc, aoff, boff, ca0, ca1, bf, acc,
                          [&] { if (!lastit) stA(0, 0, t2); }, g0);
    phase<1, 0, 1, false>(ldsc, aoff, boff, ca0, ca1, bf, acc,
                          [&] { if (!lastit) stA(0, 1, t2); }, g0);
    phase<1, 1, 0, true >(ldsc, aoff, boff, ca0, ca1, bf, acc,
                          [&] { if (!lastit) stB(0, 1, t2); }, g0);
    phase<1, 1, 1, false>(ldsc, aoff, boff, ca0, ca1, bf, acc,
                          [&] { if (!lastit) stB(1, 0, t3); }, g2);
  }

  // epilogue: C/D layout col=lane&15, row=(lane>>4)*4+reg
  #pragma unroll
  for (int m = 0; m < 8; ++m) {
    const int rbase = row0 + wm * 128 + m * 16 + (lk << 2);
    #pragma unroll
    for (int r = 0; r < 4; ++r) {
      const size_t rowoff = (size_t)(rbase + r) * N;
      #pragma unroll
      for (int n = 0; n < 4; ++n) {
        const int col = col0 + wn * 64 + n * 16 + l15;
        const float v = acc[m][n][r];
        if constexpr (OUT_HALF)
          ((_Float16*)Cout)[rowoff + col] = (_Float16)v;
        else
          ((float*)Cout)[rowoff + col] = v;
      }
    }
  }
}

// ---------------------------------------------------------------------------
// Attention: 1 wave per batch row. lane -> head h = lane>>2, part p = lane&3.
// ---------------------------------------------------------------------------
__global__ __launch_bounds__(256) void attn_kernel(
    const _Float16* __restrict__ Q16, const _Float16* __restrict__ KVR,
    _Float16* __restrict__ AV16, float* __restrict__ attn_out,
    size_t batch0)
{
  const int lane = threadIdx.x & 63;
  const int wave = threadIdx.x >> 6;
  const size_t b = (size_t)blockIdx.x * 4 + wave;
  const int h = lane >> 2, p = lane & 3;
  const int doff = h * 64 + p * 16;

  float qv[16];
  {
    const half8* qp = (const half8*)(Q16 + b * 1024 + doff);
    half8 q0 = qp[0], q1 = qp[1];
    #pragma unroll
    for (int i = 0; i < 8; ++i) { qv[i] = (float)q0[i]; qv[8 + i] = (float)q1[i]; }
  }
  float sc[LSEQ];
  #pragma unroll
  for (int l = 0; l < LSEQ; ++l) {
    const half8* kp = (const half8*)(KVR + (b * 3 + l) * 3072 + doff);
    half8 k0 = kp[0], k1 = kp[1];
    float d = 0.f;
    #pragma unroll
    for (int i = 0; i < 8; ++i)
      d += qv[i] * (float)k0[i] + qv[8 + i] * (float)k1[i];
    d += __shfl_xor(d, 1);
    d += __shfl_xor(d, 2);
    sc[l] = d * 0.125f;
  }
  const float mx = fmaxf(sc[0], fmaxf(sc[1], sc[2]));
  const float e0 = __expf(sc[0] - mx), e1 = __expf(sc[1] - mx),
              e2 = __expf(sc[2] - mx);
  const float inv = 1.f / (e0 + e1 + e2);
  const float at0 = e0 * inv, at1 = e1 * inv, at2 = e2 * inv;
  if (p == 0) {
    float* ao = attn_out + ((batch0 + b) * NH + h) * LSEQ;
    ao[0] = at0; ao[1] = at1; ao[2] = at2;
  }
  const float atw[LSEQ] = {at0, at1, at2};
  float av[16] = {};
  #pragma unroll
  for (int l = 0; l < LSEQ; ++l) {
    const half8* vp = (const half8*)(KVR + (b * 3 + l) * 3072 + 1024 + doff);
    const half8* rp = (const half8*)(KVR + (b * 3 + l) * 3072 + 2048 + doff);
    half8 v0 = vp[0], v1 = vp[1], r0 = rp[0], r1 = rp[1];
    #pragma unroll
    for (int i = 0; i < 8; ++i) {
      const float g0 = 1.f / (1.f + __expf(-(float)r0[i]));
      const float g1 = 1.f / (1.f + __expf(-(float)r1[i]));
      av[i]     += atw[l] * g0 * (float)v0[i];
      av[8 + i] += atw[l] * g1 * (float)v1[i];
    }
  }
  half8 o0, o1;
  #pragma unroll
  for (int i = 0; i < 8; ++i) { o0[i] = (_Float16)av[i]; o1[i] = (_Float16)av[8 + i]; }
  half8* op = (half8*)(AV16 + b * 1024 + doff);
  op[0] = o0; op[1] = o1;
}

// ---------------------------------------------------------------------------
// Residual + LayerNorm: 1 wave per row.
// ---------------------------------------------------------------------------
__global__ __launch_bounds__(256) void ln_kernel(
    const float* __restrict__ qres, const float* __restrict__ outlin,
    const float* __restrict__ gamma, const float* __restrict__ beta,
    float* __restrict__ out)
{
  const int lane = threadIdx.x & 63;
  const size_t r = (size_t)blockIdx.x * 4 + (threadIdx.x >> 6);
  const size_t base = r * 1024 + lane * 16;
  floatx4 y[4];
  float s = 0.f, ss = 0.f;
  #pragma unroll
  for (int i = 0; i < 4; ++i) {
    floatx4 a  = *(const floatx4*)(qres + base + i * 4);
    floatx4 bb = *(const floatx4*)(outlin + base + i * 4);
    y[i] = a + bb;
    #pragma unroll
    for (int j = 0; j < 4; ++j) { s += y[i][j]; ss += y[i][j] * y[i][j]; }
  }
  #pragma unroll
  for (int o = 1; o < 64; o <<= 1) {
    s  += __shfl_xor(s, o);
    ss += __shfl_xor(ss, o);
  }
  const float mu  = s * (1.f / 1024.f);
  const float var = ss * (1.f / 1024.f) - mu * mu;
  const float rs  = rsqrtf(var + 1e-5f);
  #pragma unroll
  for (int i = 0; i < 4; ++i) {
    floatx4 g  = *(const floatx4*)(gamma + lane * 16 + i * 4);
    floatx4 be = *(const floatx4*)(beta + lane * 16 + i * 4);
    floatx4 o;
    #pragma unroll
    for (int j = 0; j < 4; ++j)
      o[j] = (y[i][j] - mu) * rs * g[j] + be[j];
    *(floatx4*)(out + base + i * 4) = o;
  }
}

// ---------------------------------------------------------------------------
extern "C" void kernel_launch(void* const* d_in, const int* in_sizes, int n_in,
                              void* d_out, int out_size, void* d_ws, size_t ws_size,
                              hipStream_t stream)
{
  const float* q     = (const float*)d_in[0];
  const float* x     = (const float*)d_in[1];
  const float* Wq    = (const float*)d_in[2];
  const float* Wk    = (const float*)d_in[3];
  const float* Wv    = (const float*)d_in[4];
  const float* Wr    = (const float*)d_in[5];
  const float* Wo    = (const float*)d_in[6];
  const float* gamma = (const float*)d_in[7];
  const float* beta  = (const float*)d_in[8];

  float* out      = (float*)d_out;
  float* attn_out = out + (size_t)BTOT * DM;

  char* ws = (char*)d_ws;
  _Float16* Wq16   = (_Float16*)ws; ws += (size_t)1024 * 1024 * 2;
  _Float16* Wkvr16 = (_Float16*)ws; ws += (size_t)3072 * 1024 * 2;
  _Float16* Wo16   = (_Float16*)ws; ws += (size_t)1024 * 1024 * 2;

  const size_t wbytes = (size_t)10 * 1024 * 1024;
  const size_t rem = ws_size > wbytes ? ws_size - wbytes : 0;
  int CB = 128;
  for (int c = BTOT; c >= 128; c >>= 1)
    if ((size_t)c * 34816 <= rem) { CB = c; break; }

  _Float16* x16  = (_Float16*)ws; ws += (size_t)CB * 3 * 1024 * 2;
  _Float16* q16  = (_Float16*)ws; ws += (size_t)CB * 1024 * 2;
  _Float16* Q16  = (_Float16*)ws; ws += (size_t)CB * 1024 * 2;
  _Float16* KVR  = (_Float16*)ws; ws += (size_t)CB * 3 * 3072 * 2;
  _Float16* AV16 = (_Float16*)ws; ws += (size_t)CB * 1024 * 2;
  float*    OUTL = (float*)ws;

  const bool big = (CB == BTOT);   // 256-tile path needs M,3M % 256 == 0

  wconv<<<dim3(1024), dim3(256), 0, stream>>>(Wq, Wk, Wv, Wr, Wo,
                                              Wq16, Wkvr16, Wo16);

  const int xblk = (CB * LSEQ * DM) / 1024;
  const int qblk = (CB * DM) / 1024;
  for (int c = 0; c < BTOT; c += CB) {
    const float* qc = q + (size_t)c * DM;
    const float* xc = x + (size_t)c * LSEQ * DM;
    acvt<<<dim3(xblk + qblk), dim3(256), 0, stream>>>(xc, x16, qc, q16, xblk);
    if (big) {
      gemm256<true><<<dim3(1024 / 256, CB / 256), dim3(512), 0, stream>>>(
          q16, Wq16, Q16, CB, 1024, 1024);
      gemm256<true><<<dim3(3072 / 256, (3 * CB) / 256), dim3(512), 0, stream>>>(
          x16, Wkvr16, KVR, 3 * CB, 3072, 1024);
    } else {
      gemm_bt<true><<<dim3(1024 / 128, CB / 128), dim3(256), 0, stream>>>(
          q16, Wq16, Q16, CB, 1024, 1024);
      gemm_bt<true><<<dim3(3072 / 128, (3 * CB) / 128), dim3(256), 0, stream>>>(
          x16, Wkvr16, KVR, 3 * CB, 3072, 1024);
    }
    attn_kernel<<<dim3(CB / 4), dim3(256), 0, stream>>>(Q16, KVR, AV16,
                                                        attn_out, (size_t)c);
    if (big) {
      gemm256<false><<<dim3(1024 / 256, CB / 256), dim3(512), 0, stream>>>(
          AV16, Wo16, OUTL, CB, 1024, 1024);
    } else {
      gemm_bt<false><<<dim3(1024 / 128, CB / 128), dim3(256), 0, stream>>>(
          AV16, Wo16, OUTL, CB, 1024, 1024);
    }
    ln_kernel<<<dim3(CB / 4), dim3(256), 0, stream>>>(qc, OUTL, gamma, beta,
                                                      out + (size_t)c * DM);
  }
}